// Round 2
// baseline (279.466 us; speedup 1.0000x reference)
//
// Swin block fwd, MI355X gfx950. Round 2: fix output dtype (d_out is float32).
// K0: weight transposes fp32->bf16 (K-contiguous for B-fragments)
// K1: per-window fused LN1 + shift-gather + QKV + attn(softmax/rpb/mask) + proj + residual -> x2 (window-order, bf16, ws)
// K2: per-window fused LN2 + MLP(gelu exact) + residual -> out (fp32, original layout)
#include <hip/hip_runtime.h>
#include <math.h>

typedef __attribute__((ext_vector_type(8))) short bf16x8;
typedef __attribute__((ext_vector_type(4))) float f32x4;

#define DEVI __device__ __forceinline__

DEVI float b2f(unsigned int u){ union{unsigned int i; float f;} c; c.i = u<<16; return c.f; }
DEVI unsigned short f2b(float f){
  union{float f; unsigned int i;} c; c.f = f;
  unsigned int r = c.i + 0x7fffu + ((c.i>>16)&1u);
  return (unsigned short)(r>>16);
}
DEVI unsigned int pack2(float a, float b){
  return (unsigned int)f2b(a) | ((unsigned int)f2b(b)<<16);
}
DEVI void unpack8(uint4 u, float* f){
  f[0]=b2f(u.x&0xffffu); f[1]=b2f(u.x>>16);
  f[2]=b2f(u.y&0xffffu); f[3]=b2f(u.y>>16);
  f[4]=b2f(u.z&0xffffu); f[5]=b2f(u.z>>16);
  f[6]=b2f(u.w&0xffffu); f[7]=b2f(u.w>>16);
}
DEVI f32x4 mfma16(bf16x8 a, bf16x8 b, f32x4 c){
  return __builtin_amdgcn_mfma_f32_16x16x32_bf16(a, b, c, 0, 0, 0);
}
// XOR swizzles: fold row bits into byte-offset bits[4:6] -> ~2-way ds_read_b128 conflicts
DEVI int swzA(int row, int byi){ return row*256 + (byi ^ ((row&7)<<4)); }      // 64x128 bf16
DEVI int swzQ(int row, int byi){ return row*64  + (byi ^ (((row>>1)&3)<<4)); } // 64x32  bf16
DEVI int swzP(int row, int byi){ return row*128 + (byi ^ ((row&7)<<4)); }      // 64x64 / 32x64
DEVI int swzH(int row, int byi){ return row*512 + (byi ^ ((row&7)<<4)); }      // 64x256 bf16

// ---------------- K0: weight transpose fp32 -> bf16, [N][K] layout ----------------
__global__ void k_prep(const float* __restrict__ qkvw, const float* __restrict__ projw,
                       const float* __restrict__ w1,   const float* __restrict__ w2,
                       ushort* __restrict__ qkvT, ushort* __restrict__ projT,
                       ushort* __restrict__ w1T,  ushort* __restrict__ w2T)
{
  const int id = blockIdx.x*256 + threadIdx.x;                 // 0..65535
  if (id < 49152){ const int k=id/384, c=id%384; qkvT[c*128+k] = f2b(qkvw[id]); } // (128,384)->(384,128)
  if (id < 16384){ const int k=id>>7, c=id&127;  projT[c*128+k] = f2b(projw[id]); } // (128,128)T
  { const int k=id>>9, c=id&511; w1T[c*128+k] = f2b(w1[id]); }  // (128,512)->(512,128)
  { const int k=id>>7, c=id&127; w2T[c*512+k] = f2b(w2[id]); }  // (512,128)->(128,512)
}

// ---------------- K1: fused window attention ----------------
__global__ __launch_bounds__(256,2) void k_attn(
    const float*  __restrict__ x,
    const float*  __restrict__ g1, const float* __restrict__ be1,
    const ushort* __restrict__ qkvT, const float* __restrict__ qkvb,
    const ushort* __restrict__ projT, const float* __restrict__ projb,
    const float*  __restrict__ rpbt,
    ushort* __restrict__ x2w)
{
  __shared__ __align__(16) char smem[65536];
  const int tid  = threadIdx.x;
  const int wave = tid>>6, lane = tid&63;
  const int l15 = lane&15, l4 = lane>>4;
  const int wid = blockIdx.x;
  const int b   = wid>>6, wim = wid&63;
  const int wh  = wim>>3, wv = wim&7;

  char* const smA  = smem;                       // 16 KB: LN1 tile, later attn-out O
  char* const smHd = smem + 16384 + wave*12288;  // per-head 12 KB
  char* const smQ  = smHd;                       // 4 KB (64x32)
  char* const smK  = smHd + 4096;                // 4 KB
  char* const smVT = smHd + 8192;                // 4 KB (32x64, V transposed)
  char* const smP  = smHd;                       // 8 KB, overlays Q+K after scores

  const f32x4 Z = {0.f,0.f,0.f,0.f};

  // ---- Phase 1: gather (roll -4,-4) + LayerNorm1 -> smA (bf16, swizzled) ----
  {
    const int t  = tid>>2;
    const int cg = (tid&3)*32;
    const int ti = t>>3, tj = t&7;
    const int ho = (wh*8+ti+4)&63, wo = (wv*8+tj+4)&63;
    const float* src = x + ((size_t)(b*4096 + ho*64 + wo))*128 + cg;
    float v[32];
    #pragma unroll
    for(int q=0;q<8;q++){
      const float4 f4 = *(const float4*)(src + q*4);
      v[q*4+0]=f4.x; v[q*4+1]=f4.y; v[q*4+2]=f4.z; v[q*4+3]=f4.w;
    }
    float s=0.f, ss=0.f;
    #pragma unroll
    for(int e=0;e<32;e++){ s+=v[e]; ss+=v[e]*v[e]; }
    s += __shfl_xor(s,1); ss += __shfl_xor(ss,1);
    s += __shfl_xor(s,2); ss += __shfl_xor(ss,2);
    const float mean = s*(1.f/128.f);
    const float varv = fmaxf(ss*(1.f/128.f) - mean*mean, 0.f);
    const float rstd = rsqrtf(varv + 1e-5f);
    #pragma unroll
    for(int q=0;q<4;q++){
      const float4 ga = *(const float4*)(g1 +cg+q*8);
      const float4 gb = *(const float4*)(g1 +cg+q*8+4);
      const float4 ba = *(const float4*)(be1+cg+q*8);
      const float4 bb = *(const float4*)(be1+cg+q*8+4);
      const float* vp = v + q*8;
      uint4 pk;
      pk.x = pack2((vp[0]-mean)*rstd*ga.x+ba.x, (vp[1]-mean)*rstd*ga.y+ba.y);
      pk.y = pack2((vp[2]-mean)*rstd*ga.z+ba.z, (vp[3]-mean)*rstd*ga.w+ba.w);
      pk.z = pack2((vp[4]-mean)*rstd*gb.x+bb.x, (vp[5]-mean)*rstd*gb.y+bb.y);
      pk.w = pack2((vp[6]-mean)*rstd*gb.z+bb.z, (vp[7]-mean)*rstd*gb.w+bb.w);
      *(uint4*)(smA + swzA(t, cg*2 + q*16)) = pk;
    }
  }
  __syncthreads();

  // ---- Phase 2: QKV for this wave's head (Q scaled, V stored transposed) ----
  const int headc = wave*32;
  {
    #pragma unroll
    for(int s3=0;s3<3;s3++){
      f32x4 acc[4][2];
      #pragma unroll
      for(int rt=0;rt<4;rt++){ acc[rt][0]=Z; acc[rt][1]=Z; }
      const ushort* wbase = qkvT + (size_t)(s3*128 + headc)*128;
      bf16x8 bfr[2][4];
      #pragma unroll
      for(int ct=0;ct<2;ct++)
        #pragma unroll
        for(int kk=0;kk<4;kk++)
          bfr[ct][kk] = *(const bf16x8*)(wbase + (ct*16+l15)*128 + kk*32 + l4*8);
      #pragma unroll
      for(int kk=0;kk<4;kk++){
        bf16x8 afr[4];
        #pragma unroll
        for(int rt=0;rt<4;rt++)
          afr[rt] = *(const bf16x8*)(smA + swzA(rt*16+l15, kk*64 + l4*16));
        #pragma unroll
        for(int rt=0;rt<4;rt++)
          #pragma unroll
          for(int ct=0;ct<2;ct++)
            acc[rt][ct] = mfma16(afr[rt], bfr[ct][kk], acc[rt][ct]);
      }
      #pragma unroll
      for(int ct=0;ct<2;ct++){
        const int hd = ct*16 + l15;
        const float bias = qkvb[s3*128 + headc + hd];
        #pragma unroll
        for(int rt=0;rt<4;rt++){
          const int t0 = rt*16 + l4*4;
          if (s3==2){
            uint2 pk;
            pk.x = pack2(acc[rt][ct][0]+bias, acc[rt][ct][1]+bias);
            pk.y = pack2(acc[rt][ct][2]+bias, acc[rt][ct][3]+bias);
            *(uint2*)(smVT + swzP(hd, t0*2)) = pk;       // V^T[hd][tok..tok+4)
          } else {
            char* const dst = (s3==0) ? smQ : smK;
            const float sc = (s3==0) ? 0.17677669529663687f : 1.f;
            #pragma unroll
            for(int j=0;j<4;j++)
              *(ushort*)(dst + swzQ(t0+j, hd*2)) = f2b((acc[rt][ct][j]+bias)*sc);
          }
        }
      }
    }
  }
  __syncthreads();  // all waves done reading smA (it becomes O below)

  // ---- Phase 3: scores (Q K^T) + rpb + shift-mask + softmax -> P bf16 ----
  f32x4 S[4][4];
  {
    bf16x8 qfr[4], kfr[4];
    #pragma unroll
    for(int i=0;i<4;i++) qfr[i] = *(const bf16x8*)(smQ + swzQ(i*16+l15, l4*16));
    #pragma unroll
    for(int i=0;i<4;i++) kfr[i] = *(const bf16x8*)(smK + swzQ(i*16+l15, l4*16));
    #pragma unroll
    for(int rt=0;rt<4;rt++)
      #pragma unroll
      for(int ct=0;ct<4;ct++)
        S[rt][ct] = mfma16(qfr[rt], kfr[ct], Z);
  }
  const bool edge = (wh==7) || (wv==7);
  #pragma unroll
  for(int ct=0;ct<4;ct++){
    const int m = ct*16 + l15;
    const int im = m>>3, jm = m&7;
    const int regm = ((wh<7)?0:((im<4)?1:2))*3 + ((wv<7)?0:((jm<4)?1:2));
    #pragma unroll
    for(int rt=0;rt<4;rt++)
      #pragma unroll
      for(int j=0;j<4;j++){
        const int n = rt*16 + l4*4 + j;
        const int in_ = n>>3, jn = n&7;
        float add = rpbt[((in_-im+7)*15 + (jn-jm+7))*4 + wave];
        if (edge){
          const int regn = ((wh<7)?0:((in_<4)?1:2))*3 + ((wv<7)?0:((jn<4)?1:2));
          if (regn != regm) add -= 100.f;
        }
        S[rt][ct][j] += add;
      }
  }
  #pragma unroll
  for(int rt=0;rt<4;rt++)
    #pragma unroll
    for(int j=0;j<4;j++){
      float mx = fmaxf(fmaxf(S[rt][0][j],S[rt][1][j]), fmaxf(S[rt][2][j],S[rt][3][j]));
      mx = fmaxf(mx, __shfl_xor(mx,1));
      mx = fmaxf(mx, __shfl_xor(mx,2));
      mx = fmaxf(mx, __shfl_xor(mx,4));
      mx = fmaxf(mx, __shfl_xor(mx,8));
      float sm = 0.f;
      #pragma unroll
      for(int ct=0;ct<4;ct++){ const float e = __expf(S[rt][ct][j]-mx); S[rt][ct][j]=e; sm+=e; }
      sm += __shfl_xor(sm,1);
      sm += __shfl_xor(sm,2);
      sm += __shfl_xor(sm,4);
      sm += __shfl_xor(sm,8);
      const float inv = 1.f/sm;
      #pragma unroll
      for(int ct=0;ct<4;ct++) S[rt][ct][j] *= inv;
    }
  #pragma unroll
  for(int rt=0;rt<4;rt++)
    #pragma unroll
    for(int j=0;j<4;j++){
      const int n = rt*16 + l4*4 + j;
      #pragma unroll
      for(int ct=0;ct<4;ct++)
        *(ushort*)(smP + swzP(n, (ct*16+l15)*2)) = f2b(S[rt][ct][j]);
    }

  // ---- Phase 4: O = P V -> smA (bf16 row-major, all heads) ----
  {
    f32x4 O[4][2];
    #pragma unroll
    for(int rt=0;rt<4;rt++){ O[rt][0]=Z; O[rt][1]=Z; }
    #pragma unroll
    for(int kk=0;kk<2;kk++){
      bf16x8 pfr[4], vfr[2];
      #pragma unroll
      for(int rt=0;rt<4;rt++)
        pfr[rt] = *(const bf16x8*)(smP + swzP(rt*16+l15, kk*64 + l4*16));
      #pragma unroll
      for(int ct=0;ct<2;ct++)
        vfr[ct] = *(const bf16x8*)(smVT + swzP(ct*16+l15, kk*64 + l4*16));
      #pragma unroll
      for(int rt=0;rt<4;rt++)
        #pragma unroll
        for(int ct=0;ct<2;ct++)
          O[rt][ct] = mfma16(pfr[rt], vfr[ct], O[rt][ct]);
    }
    #pragma unroll
    for(int rt=0;rt<4;rt++)
      #pragma unroll
      for(int ct=0;ct<2;ct++)
        #pragma unroll
        for(int j=0;j<4;j++){
          const int t = rt*16 + l4*4 + j;
          *(ushort*)(smA + swzA(t, (headc + ct*16 + l15)*2)) = f2b(O[rt][ct][j]);
        }
  }
  __syncthreads();

  // ---- Phase 5: proj + bias + shortcut -> x2 (window-order) ----
  {
    f32x4 PR[4][2];
    #pragma unroll
    for(int rt=0;rt<4;rt++){ PR[rt][0]=Z; PR[rt][1]=Z; }
    bf16x8 pb[2][4];
    #pragma unroll
    for(int ct=0;ct<2;ct++)
      #pragma unroll
      for(int kk=0;kk<4;kk++)
        pb[ct][kk] = *(const bf16x8*)(projT + (headc+ct*16+l15)*128 + kk*32 + l4*8);
    #pragma unroll
    for(int kk=0;kk<4;kk++){
      bf16x8 afr[4];
      #pragma unroll
      for(int rt=0;rt<4;rt++)
        afr[rt] = *(const bf16x8*)(smA + swzA(rt*16+l15, kk*64 + l4*16));
      #pragma unroll
      for(int rt=0;rt<4;rt++)
        #pragma unroll
        for(int ct=0;ct<2;ct++)
          PR[rt][ct] = mfma16(afr[rt], pb[ct][kk], PR[rt][ct]);
    }
    #pragma unroll
    for(int ct=0;ct<2;ct++){
      const int col = headc + ct*16 + l15;
      const float bias = projb[col];
      #pragma unroll
      for(int rt=0;rt<4;rt++)
        #pragma unroll
        for(int j=0;j<4;j++){
          const int t = rt*16 + l4*4 + j;
          const int ti = t>>3, tj = t&7;
          const int ho = (wh*8+ti+4)&63, wo = (wv*8+tj+4)&63;
          const float sc = x[((size_t)(b*4096 + ho*64 + wo))*128 + col];
          x2w[((size_t)(wid*64 + t))*128 + col] = f2b(PR[rt][ct][j] + bias + sc);
        }
    }
  }
}

// ---------------- K2: fused MLP ----------------
__global__ __launch_bounds__(256,2) void k_mlp(
    const ushort* __restrict__ x2w,
    const float* __restrict__ g2, const float* __restrict__ be2,
    const ushort* __restrict__ w1T, const float* __restrict__ bb1,
    const ushort* __restrict__ w2T, const float* __restrict__ bb2,
    float* __restrict__ outp)
{
  __shared__ __align__(16) char smem[49152];
  char* const smA  = smem;          // 16 KB LN2 tile
  char* const smHd = smem + 16384;  // 32 KB hidden half (64x256 bf16)
  const int tid  = threadIdx.x;
  const int wave = tid>>6, lane = tid&63;
  const int l15 = lane&15, l4 = lane>>4;
  const int wid = blockIdx.x;
  const int b   = wid>>6, wim = wid&63;
  const int wh  = wim>>3, wv = wim&7;
  const f32x4 Z = {0.f,0.f,0.f,0.f};

  // LN2 on x2 rows (window order, contiguous)
  {
    const int t  = tid>>2;
    const int cg = (tid&3)*32;
    const ushort* src = x2w + ((size_t)(wid*64 + t))*128 + cg;
    float v[32];
    unpack8(*(const uint4*)(src   ), v   );
    unpack8(*(const uint4*)(src+ 8), v+ 8);
    unpack8(*(const uint4*)(src+16), v+16);
    unpack8(*(const uint4*)(src+24), v+24);
    float s=0.f, ss=0.f;
    #pragma unroll
    for(int e=0;e<32;e++){ s+=v[e]; ss+=v[e]*v[e]; }
    s += __shfl_xor(s,1); ss += __shfl_xor(ss,1);
    s += __shfl_xor(s,2); ss += __shfl_xor(ss,2);
    const float mean = s*(1.f/128.f);
    const float varv = fmaxf(ss*(1.f/128.f) - mean*mean, 0.f);
    const float rstd = rsqrtf(varv + 1e-5f);
    #pragma unroll
    for(int q=0;q<4;q++){
      const float4 ga = *(const float4*)(g2 +cg+q*8);
      const float4 gb = *(const float4*)(g2 +cg+q*8+4);
      const float4 ba = *(const float4*)(be2+cg+q*8);
      const float4 bb = *(const float4*)(be2+cg+q*8+4);
      const float* vp = v + q*8;
      uint4 pk;
      pk.x = pack2((vp[0]-mean)*rstd*ga.x+ba.x, (vp[1]-mean)*rstd*ga.y+ba.y);
      pk.y = pack2((vp[2]-mean)*rstd*ga.z+ba.z, (vp[3]-mean)*rstd*ga.w+ba.w);
      pk.z = pack2((vp[4]-mean)*rstd*gb.x+bb.x, (vp[5]-mean)*rstd*gb.y+bb.y);
      pk.w = pack2((vp[6]-mean)*rstd*gb.z+bb.z, (vp[7]-mean)*rstd*gb.w+bb.w);
      *(uint4*)(smA + swzA(t, cg*2 + q*16)) = pk;
    }
  }
  __syncthreads();

  f32x4 OA[4][2];
  #pragma unroll
  for(int rt=0;rt<4;rt++){ OA[rt][0]=Z; OA[rt][1]=Z; }

  #pragma unroll
  for(int ph=0; ph<2; ++ph){
    // GEMM1: this wave's 64 hidden cols of this half
    f32x4 HA[4][4];
    #pragma unroll
    for(int rt=0;rt<4;rt++)
      #pragma unroll
      for(int ct=0;ct<4;ct++) HA[rt][ct]=Z;
    const int c0 = ph*256 + wave*64;
    #pragma unroll
    for(int kk=0;kk<4;kk++){
      bf16x8 afr[4];
      #pragma unroll
      for(int rt=0;rt<4;rt++)
        afr[rt] = *(const bf16x8*)(smA + swzA(rt*16+l15, kk*64 + l4*16));
      bf16x8 bfr[4];
      #pragma unroll
      for(int ct=0;ct<4;ct++)
        bfr[ct] = *(const bf16x8*)(w1T + (size_t)(c0+ct*16+l15)*128 + kk*32 + l4*8);
      #pragma unroll
      for(int rt=0;rt<4;rt++)
        #pragma unroll
        for(int ct=0;ct<4;ct++)
          HA[rt][ct] = mfma16(afr[rt], bfr[ct], HA[rt][ct]);
    }
    if (ph==1) __syncthreads();   // WAR: all waves done reading smHd half 0
    #pragma unroll
    for(int ct=0;ct<4;ct++){
      const int ch = wave*64 + ct*16 + l15;   // col within half [0,256)
      const float bias = bb1[ph*256 + ch];
      #pragma unroll
      for(int rt=0;rt<4;rt++)
        #pragma unroll
        for(int j=0;j<4;j++){
          const float u = HA[rt][ct][j] + bias;
          const float gel = 0.5f*u*(1.f + erff(u*0.70710678118654752f));
          *(ushort*)(smHd + swzH(rt*16+l4*4+j, ch*2)) = f2b(gel);
        }
    }
    __syncthreads();
    // GEMM2 partial: K = this half's 256
    #pragma unroll
    for(int kk=0;kk<8;kk++){
      bf16x8 afr[4];
      #pragma unroll
      for(int rt=0;rt<4;rt++)
        afr[rt] = *(const bf16x8*)(smHd + swzH(rt*16+l15, kk*64 + l4*16));
      bf16x8 bfr[2];
      #pragma unroll
      for(int ct=0;ct<2;ct++)
        bfr[ct] = *(const bf16x8*)(w2T + (size_t)(wave*32+ct*16+l15)*512 + ph*256 + kk*32 + l4*8);
      #pragma unroll
      for(int rt=0;rt<4;rt++)
        #pragma unroll
        for(int ct=0;ct<2;ct++)
          OA[rt][ct] = mfma16(afr[rt], bfr[ct], OA[rt][ct]);
    }
  }

  // epilogue: + bias + x2, scatter to original (unshifted) layout, fp32 out
  #pragma unroll
  for(int ct=0;ct<2;ct++){
    const int col = wave*32 + ct*16 + l15;
    const float bias = bb2[col];
    #pragma unroll
    for(int rt=0;rt<4;rt++)
      #pragma unroll
      for(int j=0;j<4;j++){
        const int t = rt*16 + l4*4 + j;
        const int ti = t>>3, tj = t&7;
        const int ho = (wh*8+ti+4)&63, wo = (wv*8+tj+4)&63;
        const float xv = b2f(x2w[((size_t)(wid*64 + t))*128 + col]);
        outp[((size_t)(b*4096 + ho*64 + wo))*128 + col] = OA[rt][ct][j] + bias + xv;
      }
  }
}

extern "C" void kernel_launch(void* const* d_in, const int* in_sizes, int n_in,
                              void* d_out, int out_size, void* d_ws, size_t ws_size,
                              hipStream_t stream) {
  (void)in_sizes; (void)n_in; (void)out_size; (void)ws_size;
  const float* x     = (const float*)d_in[0];
  const float* n1g   = (const float*)d_in[1];
  const float* n1b   = (const float*)d_in[2];
  const float* qkvw  = (const float*)d_in[3];
  const float* qkvb  = (const float*)d_in[4];
  const float* projw = (const float*)d_in[5];
  const float* projb = (const float*)d_in[6];
  const float* rpbt  = (const float*)d_in[7];
  const float* n2g   = (const float*)d_in[8];
  const float* n2b   = (const float*)d_in[9];
  const float* w1    = (const float*)d_in[10];
  const float* b1    = (const float*)d_in[11];
  const float* w2    = (const float*)d_in[12];
  const float* b2    = (const float*)d_in[13];
  float* outp = (float*)d_out;

  ushort* ws    = (ushort*)d_ws;
  ushort* x2w   = ws;                  // 2048*64*128 = 16,777,216 bf16
  ushort* qkvT  = ws + 16777216;       // 49152
  ushort* projT = qkvT + 49152;        // 16384
  ushort* w1T   = projT + 16384;       // 65536
  ushort* w2T   = w1T + 65536;         // 65536   (total ws ~33.9 MB)

  k_prep<<<256, 256, 0, stream>>>(qkvw, projw, w1, w2, qkvT, projT, w1T, w2T);
  k_attn<<<2048, 256, 0, stream>>>(x, n1g, n1b, qkvT, qkvb, projT, projb, rpbt, x2w);
  k_mlp <<<2048, 256, 0, stream>>>(x2w, n2g, n2b, w1T, b1, w2T, b2, outp);
}

// Round 3
// 261.525 us; speedup vs baseline: 1.0686x; 1.0686x over previous
//
// Swin block fwd, MI355X gfx950. Round 3: k_mlp fast tanh-GELU (was erff, ~60% of instrs) + 3 blocks/CU.
// K0: weight transposes fp32->bf16 (K-contiguous for B-fragments)
// K1: per-window fused LN1 + shift-gather + QKV + attn(softmax/rpb/mask) + proj + residual -> x2 (window-order, bf16, ws)
// K2: per-window fused LN2 + MLP(gelu tanh-form) + residual -> out (fp32, original layout)
#include <hip/hip_runtime.h>
#include <math.h>

typedef __attribute__((ext_vector_type(8))) short bf16x8;
typedef __attribute__((ext_vector_type(4))) float f32x4;

#define DEVI __device__ __forceinline__

DEVI float b2f(unsigned int u){ union{unsigned int i; float f;} c; c.i = u<<16; return c.f; }
DEVI unsigned short f2b(float f){
  union{float f; unsigned int i;} c; c.f = f;
  unsigned int r = c.i + 0x7fffu + ((c.i>>16)&1u);
  return (unsigned short)(r>>16);
}
DEVI unsigned int pack2(float a, float b){
  return (unsigned int)f2b(a) | ((unsigned int)f2b(b)<<16);
}
DEVI void unpack8(uint4 u, float* f){
  f[0]=b2f(u.x&0xffffu); f[1]=b2f(u.x>>16);
  f[2]=b2f(u.y&0xffffu); f[3]=b2f(u.y>>16);
  f[4]=b2f(u.z&0xffffu); f[5]=b2f(u.z>>16);
  f[6]=b2f(u.w&0xffffu); f[7]=b2f(u.w>>16);
}
DEVI f32x4 mfma16(bf16x8 a, bf16x8 b, f32x4 c){
  return __builtin_amdgcn_mfma_f32_16x16x32_bf16(a, b, c, 0, 0, 0);
}
// tanh-form GELU: max abs err vs exact ~3e-3, ~10 VALU ops (vs erff ~25-30)
DEVI float gelu_fast(float u){
  const float y = 0.7978845608028654f*(u + 0.044715f*u*u*u);
  const float t = __expf(2.f*y);                 // v_mul + v_exp
  const float th = 1.f - 2.f/(t + 1.f);          // rcp + fma
  return 0.5f*u*(1.f + th);
}
// XOR swizzles: fold row bits into byte-offset bits[4:6] -> ~2-way ds_read_b128 conflicts
DEVI int swzA(int row, int byi){ return row*256 + (byi ^ ((row&7)<<4)); }      // 64x128 bf16
DEVI int swzQ(int row, int byi){ return row*64  + (byi ^ (((row>>1)&3)<<4)); } // 64x32  bf16
DEVI int swzP(int row, int byi){ return row*128 + (byi ^ ((row&7)<<4)); }      // 64x64 / 32x64
DEVI int swzH(int row, int byi){ return row*512 + (byi ^ ((row&7)<<4)); }      // 64x256 bf16

// ---------------- K0: weight transpose fp32 -> bf16, [N][K] layout ----------------
__global__ void k_prep(const float* __restrict__ qkvw, const float* __restrict__ projw,
                       const float* __restrict__ w1,   const float* __restrict__ w2,
                       ushort* __restrict__ qkvT, ushort* __restrict__ projT,
                       ushort* __restrict__ w1T,  ushort* __restrict__ w2T)
{
  const int id = blockIdx.x*256 + threadIdx.x;                 // 0..65535
  if (id < 49152){ const int k=id/384, c=id%384; qkvT[c*128+k] = f2b(qkvw[id]); } // (128,384)->(384,128)
  if (id < 16384){ const int k=id>>7, c=id&127;  projT[c*128+k] = f2b(projw[id]); } // (128,128)T
  { const int k=id>>9, c=id&511; w1T[c*128+k] = f2b(w1[id]); }  // (128,512)->(512,128)
  { const int k=id>>7, c=id&127; w2T[c*512+k] = f2b(w2[id]); }  // (512,128)->(128,512)
}

// ---------------- K1: fused window attention ----------------
__global__ __launch_bounds__(256,2) void k_attn(
    const float*  __restrict__ x,
    const float*  __restrict__ g1, const float* __restrict__ be1,
    const ushort* __restrict__ qkvT, const float* __restrict__ qkvb,
    const ushort* __restrict__ projT, const float* __restrict__ projb,
    const float*  __restrict__ rpbt,
    ushort* __restrict__ x2w)
{
  __shared__ __align__(16) char smem[65536];
  const int tid  = threadIdx.x;
  const int wave = tid>>6, lane = tid&63;
  const int l15 = lane&15, l4 = lane>>4;
  const int wid = blockIdx.x;
  const int b   = wid>>6, wim = wid&63;
  const int wh  = wim>>3, wv = wim&7;

  char* const smA  = smem;                       // 16 KB: LN1 tile, later attn-out O
  char* const smHd = smem + 16384 + wave*12288;  // per-head 12 KB
  char* const smQ  = smHd;                       // 4 KB (64x32)
  char* const smK  = smHd + 4096;                // 4 KB
  char* const smVT = smHd + 8192;                // 4 KB (32x64, V transposed)
  char* const smP  = smHd;                       // 8 KB, overlays Q+K after scores

  const f32x4 Z = {0.f,0.f,0.f,0.f};

  // ---- Phase 1: gather (roll -4,-4) + LayerNorm1 -> smA (bf16, swizzled) ----
  {
    const int t  = tid>>2;
    const int cg = (tid&3)*32;
    const int ti = t>>3, tj = t&7;
    const int ho = (wh*8+ti+4)&63, wo = (wv*8+tj+4)&63;
    const float* src = x + ((size_t)(b*4096 + ho*64 + wo))*128 + cg;
    float v[32];
    #pragma unroll
    for(int q=0;q<8;q++){
      const float4 f4 = *(const float4*)(src + q*4);
      v[q*4+0]=f4.x; v[q*4+1]=f4.y; v[q*4+2]=f4.z; v[q*4+3]=f4.w;
    }
    float s=0.f, ss=0.f;
    #pragma unroll
    for(int e=0;e<32;e++){ s+=v[e]; ss+=v[e]*v[e]; }
    s += __shfl_xor(s,1); ss += __shfl_xor(ss,1);
    s += __shfl_xor(s,2); ss += __shfl_xor(ss,2);
    const float mean = s*(1.f/128.f);
    const float varv = fmaxf(ss*(1.f/128.f) - mean*mean, 0.f);
    const float rstd = rsqrtf(varv + 1e-5f);
    #pragma unroll
    for(int q=0;q<4;q++){
      const float4 ga = *(const float4*)(g1 +cg+q*8);
      const float4 gb = *(const float4*)(g1 +cg+q*8+4);
      const float4 ba = *(const float4*)(be1+cg+q*8);
      const float4 bb = *(const float4*)(be1+cg+q*8+4);
      const float* vp = v + q*8;
      uint4 pk;
      pk.x = pack2((vp[0]-mean)*rstd*ga.x+ba.x, (vp[1]-mean)*rstd*ga.y+ba.y);
      pk.y = pack2((vp[2]-mean)*rstd*ga.z+ba.z, (vp[3]-mean)*rstd*ga.w+ba.w);
      pk.z = pack2((vp[4]-mean)*rstd*gb.x+bb.x, (vp[5]-mean)*rstd*gb.y+bb.y);
      pk.w = pack2((vp[6]-mean)*rstd*gb.z+bb.z, (vp[7]-mean)*rstd*gb.w+bb.w);
      *(uint4*)(smA + swzA(t, cg*2 + q*16)) = pk;
    }
  }
  __syncthreads();

  // ---- Phase 2: QKV for this wave's head (Q scaled, V stored transposed) ----
  const int headc = wave*32;
  {
    #pragma unroll
    for(int s3=0;s3<3;s3++){
      f32x4 acc[4][2];
      #pragma unroll
      for(int rt=0;rt<4;rt++){ acc[rt][0]=Z; acc[rt][1]=Z; }
      const ushort* wbase = qkvT + (size_t)(s3*128 + headc)*128;
      bf16x8 bfr[2][4];
      #pragma unroll
      for(int ct=0;ct<2;ct++)
        #pragma unroll
        for(int kk=0;kk<4;kk++)
          bfr[ct][kk] = *(const bf16x8*)(wbase + (ct*16+l15)*128 + kk*32 + l4*8);
      #pragma unroll
      for(int kk=0;kk<4;kk++){
        bf16x8 afr[4];
        #pragma unroll
        for(int rt=0;rt<4;rt++)
          afr[rt] = *(const bf16x8*)(smA + swzA(rt*16+l15, kk*64 + l4*16));
        #pragma unroll
        for(int rt=0;rt<4;rt++)
          #pragma unroll
          for(int ct=0;ct<2;ct++)
            acc[rt][ct] = mfma16(afr[rt], bfr[ct][kk], acc[rt][ct]);
      }
      #pragma unroll
      for(int ct=0;ct<2;ct++){
        const int hd = ct*16 + l15;
        const float bias = qkvb[s3*128 + headc + hd];
        #pragma unroll
        for(int rt=0;rt<4;rt++){
          const int t0 = rt*16 + l4*4;
          if (s3==2){
            uint2 pk;
            pk.x = pack2(acc[rt][ct][0]+bias, acc[rt][ct][1]+bias);
            pk.y = pack2(acc[rt][ct][2]+bias, acc[rt][ct][3]+bias);
            *(uint2*)(smVT + swzP(hd, t0*2)) = pk;       // V^T[hd][tok..tok+4)
          } else {
            char* const dst = (s3==0) ? smQ : smK;
            const float sc = (s3==0) ? 0.17677669529663687f : 1.f;
            #pragma unroll
            for(int j=0;j<4;j++)
              *(ushort*)(dst + swzQ(t0+j, hd*2)) = f2b((acc[rt][ct][j]+bias)*sc);
          }
        }
      }
    }
  }
  __syncthreads();  // all waves done reading smA (it becomes O below)

  // ---- Phase 3: scores (Q K^T) + rpb + shift-mask + softmax -> P bf16 ----
  f32x4 S[4][4];
  {
    bf16x8 qfr[4], kfr[4];
    #pragma unroll
    for(int i=0;i<4;i++) qfr[i] = *(const bf16x8*)(smQ + swzQ(i*16+l15, l4*16));
    #pragma unroll
    for(int i=0;i<4;i++) kfr[i] = *(const bf16x8*)(smK + swzQ(i*16+l15, l4*16));
    #pragma unroll
    for(int rt=0;rt<4;rt++)
      #pragma unroll
      for(int ct=0;ct<4;ct++)
        S[rt][ct] = mfma16(qfr[rt], kfr[ct], Z);
  }
  const bool edge = (wh==7) || (wv==7);
  #pragma unroll
  for(int ct=0;ct<4;ct++){
    const int m = ct*16 + l15;
    const int im = m>>3, jm = m&7;
    const int regm = ((wh<7)?0:((im<4)?1:2))*3 + ((wv<7)?0:((jm<4)?1:2));
    #pragma unroll
    for(int rt=0;rt<4;rt++)
      #pragma unroll
      for(int j=0;j<4;j++){
        const int n = rt*16 + l4*4 + j;
        const int in_ = n>>3, jn = n&7;
        float add = rpbt[((in_-im+7)*15 + (jn-jm+7))*4 + wave];
        if (edge){
          const int regn = ((wh<7)?0:((in_<4)?1:2))*3 + ((wv<7)?0:((jn<4)?1:2));
          if (regn != regm) add -= 100.f;
        }
        S[rt][ct][j] += add;
      }
  }
  #pragma unroll
  for(int rt=0;rt<4;rt++)
    #pragma unroll
    for(int j=0;j<4;j++){
      float mx = fmaxf(fmaxf(S[rt][0][j],S[rt][1][j]), fmaxf(S[rt][2][j],S[rt][3][j]));
      mx = fmaxf(mx, __shfl_xor(mx,1));
      mx = fmaxf(mx, __shfl_xor(mx,2));
      mx = fmaxf(mx, __shfl_xor(mx,4));
      mx = fmaxf(mx, __shfl_xor(mx,8));
      float sm = 0.f;
      #pragma unroll
      for(int ct=0;ct<4;ct++){ const float e = __expf(S[rt][ct][j]-mx); S[rt][ct][j]=e; sm+=e; }
      sm += __shfl_xor(sm,1);
      sm += __shfl_xor(sm,2);
      sm += __shfl_xor(sm,4);
      sm += __shfl_xor(sm,8);
      const float inv = 1.f/sm;
      #pragma unroll
      for(int ct=0;ct<4;ct++) S[rt][ct][j] *= inv;
    }
  #pragma unroll
  for(int rt=0;rt<4;rt++)
    #pragma unroll
    for(int j=0;j<4;j++){
      const int n = rt*16 + l4*4 + j;
      #pragma unroll
      for(int ct=0;ct<4;ct++)
        *(ushort*)(smP + swzP(n, (ct*16+l15)*2)) = f2b(S[rt][ct][j]);
    }

  // ---- Phase 4: O = P V -> smA (bf16 row-major, all heads) ----
  {
    f32x4 O[4][2];
    #pragma unroll
    for(int rt=0;rt<4;rt++){ O[rt][0]=Z; O[rt][1]=Z; }
    #pragma unroll
    for(int kk=0;kk<2;kk++){
      bf16x8 pfr[4], vfr[2];
      #pragma unroll
      for(int rt=0;rt<4;rt++)
        pfr[rt] = *(const bf16x8*)(smP + swzP(rt*16+l15, kk*64 + l4*16));
      #pragma unroll
      for(int ct=0;ct<2;ct++)
        vfr[ct] = *(const bf16x8*)(smVT + swzP(ct*16+l15, kk*64 + l4*16));
      #pragma unroll
      for(int rt=0;rt<4;rt++)
        #pragma unroll
        for(int ct=0;ct<2;ct++)
          O[rt][ct] = mfma16(pfr[rt], vfr[ct], O[rt][ct]);
    }
    #pragma unroll
    for(int rt=0;rt<4;rt++)
      #pragma unroll
      for(int ct=0;ct<2;ct++)
        #pragma unroll
        for(int j=0;j<4;j++){
          const int t = rt*16 + l4*4 + j;
          *(ushort*)(smA + swzA(t, (headc + ct*16 + l15)*2)) = f2b(O[rt][ct][j]);
        }
  }
  __syncthreads();

  // ---- Phase 5: proj + bias + shortcut -> x2 (window-order) ----
  {
    f32x4 PR[4][2];
    #pragma unroll
    for(int rt=0;rt<4;rt++){ PR[rt][0]=Z; PR[rt][1]=Z; }
    bf16x8 pb[2][4];
    #pragma unroll
    for(int ct=0;ct<2;ct++)
      #pragma unroll
      for(int kk=0;kk<4;kk++)
        pb[ct][kk] = *(const bf16x8*)(projT + (headc+ct*16+l15)*128 + kk*32 + l4*8);
    #pragma unroll
    for(int kk=0;kk<4;kk++){
      bf16x8 afr[4];
      #pragma unroll
      for(int rt=0;rt<4;rt++)
        afr[rt] = *(const bf16x8*)(smA + swzA(rt*16+l15, kk*64 + l4*16));
      #pragma unroll
      for(int rt=0;rt<4;rt++)
        #pragma unroll
        for(int ct=0;ct<2;ct++)
          PR[rt][ct] = mfma16(afr[rt], pb[ct][kk], PR[rt][ct]);
    }
    #pragma unroll
    for(int ct=0;ct<2;ct++){
      const int col = headc + ct*16 + l15;
      const float bias = projb[col];
      #pragma unroll
      for(int rt=0;rt<4;rt++)
        #pragma unroll
        for(int j=0;j<4;j++){
          const int t = rt*16 + l4*4 + j;
          const int ti = t>>3, tj = t&7;
          const int ho = (wh*8+ti+4)&63, wo = (wv*8+tj+4)&63;
          const float sc = x[((size_t)(b*4096 + ho*64 + wo))*128 + col];
          x2w[((size_t)(wid*64 + t))*128 + col] = f2b(PR[rt][ct][j] + bias + sc);
        }
    }
  }
}

// ---------------- K2: fused MLP ----------------
__global__ __launch_bounds__(256,3) void k_mlp(
    const ushort* __restrict__ x2w,
    const float* __restrict__ g2, const float* __restrict__ be2,
    const ushort* __restrict__ w1T, const float* __restrict__ bb1,
    const ushort* __restrict__ w2T, const float* __restrict__ bb2,
    float* __restrict__ outp)
{
  __shared__ __align__(16) char smem[49152];
  char* const smA  = smem;          // 16 KB LN2 tile
  char* const smHd = smem + 16384;  // 32 KB hidden half (64x256 bf16)
  const int tid  = threadIdx.x;
  const int wave = tid>>6, lane = tid&63;
  const int l15 = lane&15, l4 = lane>>4;
  const int wid = blockIdx.x;
  const int b   = wid>>6, wim = wid&63;
  const int wh  = wim>>3, wv = wim&7;
  const f32x4 Z = {0.f,0.f,0.f,0.f};

  // LN2 on x2 rows (window order, contiguous)
  {
    const int t  = tid>>2;
    const int cg = (tid&3)*32;
    const ushort* src = x2w + ((size_t)(wid*64 + t))*128 + cg;
    float v[32];
    unpack8(*(const uint4*)(src   ), v   );
    unpack8(*(const uint4*)(src+ 8), v+ 8);
    unpack8(*(const uint4*)(src+16), v+16);
    unpack8(*(const uint4*)(src+24), v+24);
    float s=0.f, ss=0.f;
    #pragma unroll
    for(int e=0;e<32;e++){ s+=v[e]; ss+=v[e]*v[e]; }
    s += __shfl_xor(s,1); ss += __shfl_xor(ss,1);
    s += __shfl_xor(s,2); ss += __shfl_xor(ss,2);
    const float mean = s*(1.f/128.f);
    const float varv = fmaxf(ss*(1.f/128.f) - mean*mean, 0.f);
    const float rstd = rsqrtf(varv + 1e-5f);
    #pragma unroll
    for(int q=0;q<4;q++){
      const float4 ga = *(const float4*)(g2 +cg+q*8);
      const float4 gb = *(const float4*)(g2 +cg+q*8+4);
      const float4 ba = *(const float4*)(be2+cg+q*8);
      const float4 bb = *(const float4*)(be2+cg+q*8+4);
      const float* vp = v + q*8;
      uint4 pk;
      pk.x = pack2((vp[0]-mean)*rstd*ga.x+ba.x, (vp[1]-mean)*rstd*ga.y+ba.y);
      pk.y = pack2((vp[2]-mean)*rstd*ga.z+ba.z, (vp[3]-mean)*rstd*ga.w+ba.w);
      pk.z = pack2((vp[4]-mean)*rstd*gb.x+bb.x, (vp[5]-mean)*rstd*gb.y+bb.y);
      pk.w = pack2((vp[6]-mean)*rstd*gb.z+bb.z, (vp[7]-mean)*rstd*gb.w+bb.w);
      *(uint4*)(smA + swzA(t, cg*2 + q*16)) = pk;
    }
  }
  __syncthreads();

  f32x4 OA[4][2];
  #pragma unroll
  for(int rt=0;rt<4;rt++){ OA[rt][0]=Z; OA[rt][1]=Z; }

  #pragma unroll
  for(int ph=0; ph<2; ++ph){
    // GEMM1: this wave's 64 hidden cols of this half
    f32x4 HA[4][4];
    #pragma unroll
    for(int rt=0;rt<4;rt++)
      #pragma unroll
      for(int ct=0;ct<4;ct++) HA[rt][ct]=Z;
    const int c0 = ph*256 + wave*64;
    #pragma unroll
    for(int kk=0;kk<4;kk++){
      bf16x8 afr[4];
      #pragma unroll
      for(int rt=0;rt<4;rt++)
        afr[rt] = *(const bf16x8*)(smA + swzA(rt*16+l15, kk*64 + l4*16));
      bf16x8 bfr[4];
      #pragma unroll
      for(int ct=0;ct<4;ct++)
        bfr[ct] = *(const bf16x8*)(w1T + (size_t)(c0+ct*16+l15)*128 + kk*32 + l4*8);
      #pragma unroll
      for(int rt=0;rt<4;rt++)
        #pragma unroll
        for(int ct=0;ct<4;ct++)
          HA[rt][ct] = mfma16(afr[rt], bfr[ct], HA[rt][ct]);
    }
    if (ph==1) __syncthreads();   // WAR: all waves done reading smHd half 0
    #pragma unroll
    for(int ct=0;ct<4;ct++){
      const int ch = wave*64 + ct*16 + l15;   // col within half [0,256)
      const float bias = bb1[ph*256 + ch];
      #pragma unroll
      for(int rt=0;rt<4;rt++)
        #pragma unroll
        for(int j=0;j<4;j++){
          const float u = HA[rt][ct][j] + bias;
          *(ushort*)(smHd + swzH(rt*16+l4*4+j, ch*2)) = f2b(gelu_fast(u));
        }
    }
    __syncthreads();
    // GEMM2 partial: K = this half's 256
    #pragma unroll
    for(int kk=0;kk<8;kk++){
      bf16x8 afr[4];
      #pragma unroll
      for(int rt=0;rt<4;rt++)
        afr[rt] = *(const bf16x8*)(smHd + swzH(rt*16+l15, kk*64 + l4*16));
      bf16x8 bfr[2];
      #pragma unroll
      for(int ct=0;ct<2;ct++)
        bfr[ct] = *(const bf16x8*)(w2T + (size_t)(wave*32+ct*16+l15)*512 + ph*256 + kk*32 + l4*8);
      #pragma unroll
      for(int rt=0;rt<4;rt++)
        #pragma unroll
        for(int ct=0;ct<2;ct++)
          OA[rt][ct] = mfma16(afr[rt], bfr[ct], OA[rt][ct]);
    }
  }

  // epilogue: + bias + x2, scatter to original (unshifted) layout, fp32 out
  #pragma unroll
  for(int ct=0;ct<2;ct++){
    const int col = wave*32 + ct*16 + l15;
    const float bias = bb2[col];
    #pragma unroll
    for(int rt=0;rt<4;rt++)
      #pragma unroll
      for(int j=0;j<4;j++){
        const int t = rt*16 + l4*4 + j;
        const int ti = t>>3, tj = t&7;
        const int ho = (wh*8+ti+4)&63, wo = (wv*8+tj+4)&63;
        const float xv = b2f(x2w[((size_t)(wid*64 + t))*128 + col]);
        outp[((size_t)(b*4096 + ho*64 + wo))*128 + col] = OA[rt][ct][j] + bias + xv;
      }
  }
}

extern "C" void kernel_launch(void* const* d_in, const int* in_sizes, int n_in,
                              void* d_out, int out_size, void* d_ws, size_t ws_size,
                              hipStream_t stream) {
  (void)in_sizes; (void)n_in; (void)out_size; (void)ws_size;
  const float* x     = (const float*)d_in[0];
  const float* n1g   = (const float*)d_in[1];
  const float* n1b   = (const float*)d_in[2];
  const float* qkvw  = (const float*)d_in[3];
  const float* qkvb  = (const float*)d_in[4];
  const float* projw = (const float*)d_in[5];
  const float* projb = (const float*)d_in[6];
  const float* rpbt  = (const float*)d_in[7];
  const float* n2g   = (const float*)d_in[8];
  const float* n2b   = (const float*)d_in[9];
  const float* w1    = (const float*)d_in[10];
  const float* b1    = (const float*)d_in[11];
  const float* w2    = (const float*)d_in[12];
  const float* b2    = (const float*)d_in[13];
  float* outp = (float*)d_out;

  ushort* ws    = (ushort*)d_ws;
  ushort* x2w   = ws;                  // 2048*64*128 = 16,777,216 bf16
  ushort* qkvT  = ws + 16777216;       // 49152
  ushort* projT = qkvT + 49152;        // 16384
  ushort* w1T   = projT + 16384;       // 65536
  ushort* w2T   = w1T + 65536;         // 65536   (total ws ~33.9 MB)

  k_prep<<<256, 256, 0, stream>>>(qkvw, projw, w1, w2, qkvT, projT, w1T, w2T);
  k_attn<<<2048, 256, 0, stream>>>(x, n1g, n1b, qkvT, qkvb, projT, projb, rpbt, x2w);
  k_mlp <<<2048, 256, 0, stream>>>(x2w, n2g, n2b, w1T, b1, w2T, b2, outp);
}